// Round 2
// baseline (93.478 us; speedup 1.0000x reference)
//
#include <hip/hip_runtime.h>
#include <stdint.h>

#define BB 64
#define LL 16384
#define PP 256
#define NT 1024
#define TT 16   // LL / NT tokens per thread

// Block-wide exclusive scan over NT=1024 threads (16 waves of 64).
// Leading __syncthreads protects s_wave/s_total reuse across calls.
__device__ __forceinline__ int block_exscan(int v, int tid, int* s_wave, int* s_total) {
    __syncthreads();
    const int lane = tid & 63;
    const int wv = tid >> 6;
    int inc = v;
#pragma unroll
    for (int off = 1; off < 64; off <<= 1) {
        int n = __shfl_up(inc, off, 64);
        if (lane >= off) inc += n;
    }
    if (lane == 63) s_wave[wv] = inc;
    __syncthreads();
    if (wv == 0) {
        int wval = (lane < 16) ? s_wave[lane] : 0;
        int winc = wval;
#pragma unroll
        for (int off = 1; off < 16; off <<= 1) {
            int n = __shfl_up(winc, off, 64);
            if (lane >= off) winc += n;
        }
        if (lane < 16) s_wave[lane] = winc - wval;   // exclusive wave offsets
        if (lane == 15) *s_total = winc;             // block total
    }
    __syncthreads();
    return inc - v + s_wave[wv];
}

__global__ void __launch_bounds__(NT) seg_kernel(
    const int* __restrict__ g_ids,
    const int* __restrict__ g_amask,
    const int* __restrict__ g_t2p,
    const int* __restrict__ g_kp,     // numpy bool marshalled as int32 (0/1)
    const int* __restrict__ g_qp,
    int* __restrict__ g_out)
{
    __shared__ unsigned int segbits[LL / 32];   // 2 KB: per-segment "any kept in ctx"
    __shared__ unsigned char kp[PP];
    __shared__ int s_wave[16];
    __shared__ int s_total;

    const int b = blockIdx.x;
    const int tid = threadIdx.x;
    const int tbase = tid * TT;
    const int rowoff = b * LL;

    for (int i = tid; i < LL / 32; i += NT) segbits[i] = 0u;
    if (tid < PP) kp[tid] = (g_kp[b * PP + tid] != 0);

    int qp = g_qp[b];
    qp = qp < 0 ? 0 : (qp > LL - 1 ? LL - 1 : qp);
    __syncthreads();

    // ---- load 16 contiguous tokens per thread, build per-token bitmasks ----
    int myids[TT];
    unsigned validbits = 0u, bndbits = 0u, mask1bits = 0u;
    {
        const int4* idp = (const int4*)(g_ids   + rowoff + tbase);
        const int4* amp = (const int4*)(g_amask + rowoff + tbase);
        const int4* tpp = (const int4*)(g_t2p   + rowoff + tbase);
#pragma unroll
        for (int jv = 0; jv < TT / 4; ++jv) {
            int4 iv = idp[jv];
            int4 av = amp[jv];
            int4 pv = tpp[jv];
            int idsv[4] = {iv.x, iv.y, iv.z, iv.w};
            int amv[4]  = {av.x, av.y, av.z, av.w};
            int tpv[4]  = {pv.x, pv.y, pv.z, pv.w};
#pragma unroll
            for (int k = 0; k < 4; ++k) {
                const int j = jv * 4 + k;
                myids[j] = idsv[k];
                const int va = (amv[k] != 0);
                const int bd = va && (idsv[k] == 13 || idsv[k] == 30);
                int pg = tpv[k];
                pg = pg < 0 ? 0 : (pg > PP - 1 ? PP - 1 : pg);
                const int pk = (kp[pg] != 0);
                const int gpos = tbase + j;
                const int m1 = va && (pk || gpos >= qp);   // mask0 | (tail & valid)
                validbits |= (unsigned)va << j;
                bndbits   |= (unsigned)bd << j;
                mask1bits |= (unsigned)m1 << j;
            }
        }
    }

    // ---- segment ids: block exclusive scan of boundary counts ----
    const int bcnt = __popc(bndbits);
    const int seg_base = block_exscan(bcnt, tid, s_wave, &s_total);

    // in-context bits for this thread's 16 tokens
    unsigned ctxbits;
    {
        const int rel = qp - tbase;
        ctxbits = (rel <= 0) ? 0u : ((rel >= TT) ? 0xFFFFu : ((1u << rel) - 1u));
    }

    // ---- rescue accumulate: any kept in-ctx token sets its segment bit ----
    {
        unsigned cands = mask1bits & ctxbits;   // in-ctx => tail false => this is mask0
        unsigned lsk = 0u;                      // local-segment keep flags (bits 0..16)
        while (cands) {
            const int j = __ffs(cands) - 1;
            cands &= cands - 1;
            lsk |= 1u << __popc(bndbits & ((1u << j) - 1u));
        }
        while (lsk) {
            const int j2 = __ffs(lsk) - 1;
            lsk &= lsk - 1;
            const int s = seg_base + j2;
            const unsigned w = (unsigned)s >> 5, m = 1u << (s & 31);
            if ((segbits[w] & m) == 0u) atomicOr(&segbits[w], m);  // pre-check kills contention
        }
    }
    __syncthreads();

    // ---- rescue read: in-ctx valid not-yet-kept tokens check their segment ----
    unsigned mask2bits = mask1bits;
    {
        unsigned cand = validbits & ctxbits & ~mask1bits;
        while (cand) {
            const int j = __ffs(cand) - 1;
            cand &= cand - 1;
            const int s = seg_base + __popc(bndbits & ((1u << j) - 1u));
            if (segbits[(unsigned)s >> 5] & (1u << (s & 31))) mask2bits |= 1u << j;
        }
    }

    // ---- compaction scan ----
    const int kc = __popc(mask2bits);
    const int cbase = block_exscan(kc, tid, s_wave, &s_total);
    int lk = s_total;

    // ---- fallback: nothing kept -> keep last valid token (or pos 0) ----
    if (lk == 0) {
        int lv = -1;
#pragma unroll
        for (int j = 0; j < TT; ++j)
            if ((validbits >> j) & 1u) lv = tbase + j;
#pragma unroll
        for (int off = 32; off >= 1; off >>= 1) {
            int n = __shfl_down(lv, off, 64);
            lv = lv > n ? lv : n;
        }
        __syncthreads();
        if ((tid & 63) == 0) s_wave[tid >> 6] = lv;
        __syncthreads();
        if (tid == 0) {
            int m = -1;
            for (int w = 0; w < 16; ++w) m = m > s_wave[w] ? m : s_wave[w];
            const int p = m < 0 ? 0 : m;
            g_out[rowoff + 0] = g_ids[rowoff + p];
        }
        lk = 1;
        mask2bits = 0u;   // suppress normal scatter
    }

    // ---- scatter kept ids (stable; destinations monotone -> coalesced-ish) ----
    {
        int c = rowoff + cbase;
        unsigned mm = mask2bits;
        while (mm) {
            const int j = __ffs(mm) - 1;
            mm &= mm - 1;
            g_out[c++] = myids[j];
        }
    }

    // ---- fill attn_comp, pos_comp, and pad ids_comp ----
    {
        int* attn_out = g_out + (size_t)BB * LL;
        int* pos_out  = g_out + (size_t)2 * BB * LL;
#pragma unroll
        for (int jv = 0; jv < TT / 4; ++jv) {
            const int i0 = tbase + jv * 4;
            int4 a, p;
            a.x = (i0 + 0) < lk; a.y = (i0 + 1) < lk;
            a.z = (i0 + 2) < lk; a.w = (i0 + 3) < lk;
            p.x = (i0 + 0) < lk ? (i0 + 0) : 0;
            p.y = (i0 + 1) < lk ? (i0 + 1) : 0;
            p.z = (i0 + 2) < lk ? (i0 + 2) : 0;
            p.w = (i0 + 3) < lk ? (i0 + 3) : 0;
            *((int4*)(attn_out + rowoff + i0)) = a;
            *((int4*)(pos_out  + rowoff + i0)) = p;
        }
#pragma unroll
        for (int j = 0; j < TT; ++j) {
            const int i = tbase + j;
            if (i >= lk) g_out[rowoff + i] = 0;
        }
    }
}

extern "C" void kernel_launch(void* const* d_in, const int* in_sizes, int n_in,
                              void* d_out, int out_size, void* d_ws, size_t ws_size,
                              hipStream_t stream) {
    const int* ids  = (const int*)d_in[0];
    const int* am   = (const int*)d_in[1];
    const int* t2p  = (const int*)d_in[2];
    const int* kpg  = (const int*)d_in[3];
    const int* qp   = (const int*)d_in[4];
    int* out        = (int*)d_out;
    seg_kernel<<<BB, NT, 0, stream>>>(ids, am, t2p, kpg, qp, out);
}

// Round 3
// 83.895 us; speedup vs baseline: 1.1142x; 1.1142x over previous
//
#include <hip/hip_runtime.h>
#include <stdint.h>

#define BB 64
#define LL 16384
#define PP 256
#define WW (LL / 32)   // 512 bit-words per row
#define NT2 512        // K2 threads (one per word)

// ---------------- K1: inputs -> bit arrays (valid/boundary/mask1) ----------------
__global__ void __launch_bounds__(256) k1_masks(
    const int* __restrict__ g_ids, const int* __restrict__ g_amask,
    const int* __restrict__ g_t2p, const int* __restrict__ g_kp,
    const int* __restrict__ g_qp,
    unsigned* __restrict__ validw, unsigned* __restrict__ bndw,
    unsigned* __restrict__ mask1w)
{
    __shared__ unsigned char kp[PP];
    const int chunk = blockIdx.x;    // 0..7  (2048 tokens each)
    const int row   = blockIdx.y;    // 0..63
    const int t     = threadIdx.x;   // 0..255, 8 tokens each
    if (t < PP) kp[t] = (g_kp[row * PP + t] != 0);
    int qp = g_qp[row];
    qp = qp < 0 ? 0 : (qp > LL - 1 ? LL - 1 : qp);
    __syncthreads();

    const int pos0 = chunk * 2048 + t * 8;
    const int g = row * LL + pos0;
    const int4* idp = (const int4*)(g_ids + g);
    const int4* amp = (const int4*)(g_amask + g);
    const int4* tpp = (const int4*)(g_t2p + g);
    unsigned v8 = 0, b8 = 0, m8 = 0;
#pragma unroll
    for (int jv = 0; jv < 2; ++jv) {
        int4 iv = idp[jv], av = amp[jv], pv = tpp[jv];
        int idsv[4] = {iv.x, iv.y, iv.z, iv.w};
        int amv[4]  = {av.x, av.y, av.z, av.w};
        int tpv[4]  = {pv.x, pv.y, pv.z, pv.w};
#pragma unroll
        for (int k = 0; k < 4; ++k) {
            const int j = jv * 4 + k;
            const int va = (amv[k] != 0);
            const int bd = va && (idsv[k] == 13 || idsv[k] == 30);
            int pg = tpv[k];
            pg = pg < 0 ? 0 : (pg > PP - 1 ? PP - 1 : pg);
            const int m1 = va && (kp[pg] || (pos0 + j) >= qp);
            v8 |= (unsigned)va << j;
            b8 |= (unsigned)bd << j;
            m8 |= (unsigned)m1 << j;
        }
    }
    // combine 4 adjacent lanes' bytes into one 32-token word
    const int sub = t & 3, sh = 8 * sub;
    unsigned vw = v8 << sh, bw = b8 << sh, mw = m8 << sh;
    vw |= __shfl_xor(vw, 1, 64); vw |= __shfl_xor(vw, 2, 64);
    bw |= __shfl_xor(bw, 1, 64); bw |= __shfl_xor(bw, 2, 64);
    mw |= __shfl_xor(mw, 1, 64); mw |= __shfl_xor(mw, 2, 64);
    if (sub == 0) {
        const int widx = row * WW + chunk * 64 + (t >> 2);
        validw[widx] = vw; bndw[widx] = bw; mask1w[widx] = mw;
    }
}

// Block exclusive scan over 512 threads (8 waves of 64).
__device__ __forceinline__ int exscan512(int v, int tid, int* s_wave, int* s_total) {
    __syncthreads();
    const int lane = tid & 63, wv = tid >> 6;
    int inc = v;
#pragma unroll
    for (int off = 1; off < 64; off <<= 1) {
        int n = __shfl_up(inc, off, 64);
        if (lane >= off) inc += n;
    }
    if (lane == 63) s_wave[wv] = inc;
    __syncthreads();
    if (wv == 0) {
        int wval = (lane < 8) ? s_wave[lane] : 0;
        int winc = wval;
#pragma unroll
        for (int off = 1; off < 8; off <<= 1) {
            int n = __shfl_up(winc, off, 64);
            if (lane >= off) winc += n;
        }
        if (lane < 8) s_wave[lane] = winc - wval;
        if (lane == 7) *s_total = winc;
    }
    __syncthreads();
    return inc - v + s_wave[wv];
}

// ---------------- K2: scans + sentence rescue + fallback (one block per row) ----------------
__global__ void __launch_bounds__(NT2) k2_scan(
    const unsigned* __restrict__ validw, const unsigned* __restrict__ bndw,
    const unsigned* __restrict__ mask1w, const int* __restrict__ g_qp,
    unsigned* __restrict__ mask2w, int* __restrict__ wordscan,
    int* __restrict__ lkarr)
{
    __shared__ unsigned segbits[WW];   // 2 KB: one bit per possible segment id
    __shared__ int s_wave[8];
    __shared__ int s_total;
    __shared__ int s_fb;
    const int row = blockIdx.x;
    const int t = threadIdx.x;         // word index 0..511
    segbits[t] = 0u;
    int qp = g_qp[row];
    qp = qp < 0 ? 0 : (qp > LL - 1 ? LL - 1 : qp);
    const unsigned vwd = validw[row * WW + t];
    const unsigned bwd = bndw[row * WW + t];
    const unsigned mwd = mask1w[row * WW + t];

    // segment id base for this word = boundaries before it (exscan syncs cover segbits init)
    const int segbase = exscan512(__popc(bwd), t, s_wave, &s_total);

    // in-context bits of this word
    const int rel = qp - t * 32;
    const unsigned ctx = rel <= 0 ? 0u : (rel >= 32 ? 0xFFFFFFFFu : ((1u << rel) - 1u));

    // rescue accumulate: kept in-ctx tokens set their segment's bit
    {
        unsigned cands = mwd & ctx;   // in-ctx => tail false => this is mask0
        if (bwd == 0u) {
            if (cands) {
                const unsigned w_ = (unsigned)segbase >> 5, m_ = 1u << (segbase & 31);
                if ((segbits[w_] & m_) == 0u) atomicOr(&segbits[w_], m_);
            }
        } else {
            while (cands) {
                const int j = __ffs(cands) - 1;
                cands &= cands - 1;
                const int s = segbase + __popc(bwd & ((1u << j) - 1u));
                const unsigned w_ = (unsigned)s >> 5, m_ = 1u << (s & 31);
                if ((segbits[w_] & m_) == 0u) atomicOr(&segbits[w_], m_);
            }
        }
    }
    __syncthreads();

    // rescue read: in-ctx valid not-yet-kept tokens join if their segment bit is set
    unsigned m2 = mwd;
    {
        unsigned cand = vwd & ctx & ~mwd;
        if (bwd == 0u) {
            if (cand && ((segbits[(unsigned)segbase >> 5] >> (segbase & 31)) & 1u)) m2 |= cand;
        } else {
            while (cand) {
                const int j = __ffs(cand) - 1;
                cand &= cand - 1;
                const int s = segbase + __popc(bwd & ((1u << j) - 1u));
                if ((segbits[(unsigned)s >> 5] >> (s & 31)) & 1u) m2 |= 1u << j;
            }
        }
    }

    // compaction scan
    int cb = exscan512(__popc(m2), t, s_wave, &s_total);
    int lk = s_total;

    // fallback: nothing kept -> keep last valid token (or position 0)
    if (lk == 0) {
        int lastv = vwd ? t * 32 + (31 - __clz(vwd)) : -1;
#pragma unroll
        for (int off = 32; off >= 1; off >>= 1) {
            int n = __shfl_down(lastv, off, 64);
            lastv = lastv > n ? lastv : n;
        }
        __syncthreads();
        if ((t & 63) == 0) s_wave[t >> 6] = lastv;
        __syncthreads();
        if (t == 0) {
            int m = -1;
            for (int w = 0; w < 8; ++w) m = m > s_wave[w] ? m : s_wave[w];
            s_fb = m < 0 ? 0 : m;
        }
        __syncthreads();
        const int fb = s_fb, fw = fb >> 5;
        m2 = (t == fw) ? (1u << (fb & 31)) : 0u;
        cb = (t > fw) ? 1 : 0;
        lk = 1;
    }

    mask2w[row * WW + t] = m2;
    wordscan[row * WW + t] = cb;
    if (t == 0) lkarr[row] = lk;
}

// ---------------- K3: scatter-compact ids + attn/pos/pad ----------------
__global__ void __launch_bounds__(256) k3_write(
    const int* __restrict__ g_ids, const unsigned* __restrict__ mask2w,
    const int* __restrict__ wordscan, const int* __restrict__ lkarr,
    int* __restrict__ g_out)
{
    const int chunk = blockIdx.x;    // 0..7
    const int row   = blockIdx.y;    // 0..63
    const int t     = threadIdx.x;   // 0..255, 8 tokens each
    const int pos0 = chunk * 2048 + t * 8;
    const int widx = row * WW + (pos0 >> 5);
    const unsigned m2 = mask2w[widx];
    const int base = wordscan[widx];
    const int lk = lkarr[row];
    const int sub = t & 3;
    const unsigned mybits = (m2 >> (8 * sub)) & 0xffu;
    const int off = base + __popc(m2 & ((1u << (8 * sub)) - 1u));

    const int g = row * LL + pos0;
    const int4* idp = (const int4*)(g_ids + g);
    int4 i0 = idp[0], i1 = idp[1];

    // scatter kept ids (stable, monotone destinations)
    const int c = row * LL + off;
    if (mybits == 0xffu && (off & 3) == 0) {
        ((int4*)(g_out + c))[0] = i0;
        ((int4*)(g_out + c))[1] = i1;
    } else if (mybits) {
        int idsv[8] = {i0.x, i0.y, i0.z, i0.w, i1.x, i1.y, i1.z, i1.w};
        int cc = c;
        unsigned mm = mybits;
        while (mm) {
            const int j = __ffs(mm) - 1;
            mm &= mm - 1;
            g_out[cc++] = idsv[j];
        }
    }

    // pad ids tail
    if (pos0 + 7 >= lk) {
#pragma unroll
        for (int j = 0; j < 8; ++j)
            if (pos0 + j >= lk) g_out[g + j] = 0;
    }

    // attn / pos
    int* attn = g_out + (size_t)BB * LL;
    int* pos  = g_out + (size_t)2 * BB * LL;
    int4 a0, a1, p0, p1;
    a0.x = (pos0 + 0) < lk; a0.y = (pos0 + 1) < lk; a0.z = (pos0 + 2) < lk; a0.w = (pos0 + 3) < lk;
    a1.x = (pos0 + 4) < lk; a1.y = (pos0 + 5) < lk; a1.z = (pos0 + 6) < lk; a1.w = (pos0 + 7) < lk;
    p0.x = a0.x ? pos0 + 0 : 0; p0.y = a0.y ? pos0 + 1 : 0; p0.z = a0.z ? pos0 + 2 : 0; p0.w = a0.w ? pos0 + 3 : 0;
    p1.x = a1.x ? pos0 + 4 : 0; p1.y = a1.y ? pos0 + 5 : 0; p1.z = a1.z ? pos0 + 6 : 0; p1.w = a1.w ? pos0 + 7 : 0;
    ((int4*)(attn + g))[0] = a0;
    ((int4*)(attn + g))[1] = a1;
    ((int4*)(pos + g))[0] = p0;
    ((int4*)(pos + g))[1] = p1;
}

extern "C" void kernel_launch(void* const* d_in, const int* in_sizes, int n_in,
                              void* d_out, int out_size, void* d_ws, size_t ws_size,
                              hipStream_t stream) {
    const int* ids = (const int*)d_in[0];
    const int* am  = (const int*)d_in[1];
    const int* t2p = (const int*)d_in[2];
    const int* kpg = (const int*)d_in[3];
    const int* qp  = (const int*)d_in[4];
    int* out       = (int*)d_out;

    unsigned* validw = (unsigned*)d_ws;
    unsigned* bndw   = validw + BB * WW;
    unsigned* mask1w = bndw + BB * WW;
    unsigned* mask2w = mask1w + BB * WW;
    int* wordscan    = (int*)(mask2w + BB * WW);
    int* lkarr       = wordscan + BB * WW;

    dim3 gridA(8, BB);
    k1_masks<<<gridA, 256, 0, stream>>>(ids, am, t2p, kpg, qp, validw, bndw, mask1w);
    k2_scan<<<BB, NT2, 0, stream>>>(validw, bndw, mask1w, qp, mask2w, wordscan, lkarr);
    k3_write<<<gridA, 256, 0, stream>>>(ids, mask2w, wordscan, lkarr, out);
}